// Round 11
// baseline (169.980 us; speedup 1.0000x reference)
//
#include <hip/hip_runtime.h>
#include <hip/hip_bf16.h>
#include <hip/hip_fp16.h>

constexpr int N_   = 50000;
constexpr int E_   = 800000;
constexpr int G_   = 256;
constexpr int IN_  = 64;
constexpr int H_   = 8;
constexpr int OUT_ = 128;   // H*C
constexpr float NEG_SLOPE = 0.2f;
constexpr int NBUCK = (N_ + 255) / 256;     // 196 dst-buckets (dst>>8)
constexpr int EPB   = 4096;                 // edges per bin block
constexpr int NBINB = (E_ + EPB - 1) / EPB; // 196 bin blocks
constexpr int CAP   = 6144;                 // bucket capacity
constexpr int NXF   = (N_ + 63) / 64;       // 782 xform blocks

typedef _Float16 f16x8 __attribute__((ext_vector_type(8)));
typedef float    f32x4 __attribute__((ext_vector_type(4)));

// ---- workspace layout (byte offsets, 256B-aligned) ----
constexpr size_t OFF_X      = 0;                                   // [N,128] f16 xh
constexpr size_t OFF_EMBH   = OFF_X      + (size_t)N_*OUT_*2;      // [N,128] f16 emb
constexpr size_t OFF_ASRC   = OFF_X      + (size_t)N_*OUT_*4;      // [N,8] f32
constexpr size_t OFF_ADST   = OFF_ASRC   + (size_t)N_*H_*4;        // [N,8] f32
constexpr size_t OFF_PAIRS  = OFF_ADST   + (size_t)N_*H_*4;        // [NBUCK*CAP] u32
constexpr size_t OFF_BCNT   = OFF_PAIRS  + (size_t)NBUCK*CAP*4;    // [NBUCK] int
constexpr size_t OFF_WT     = OFF_BCNT   + 1024;                   // [128,128] f16 W1a^T
constexpr size_t OFF_WP     = OFF_WT     + 128*128*2;              // [144,64] f16 Wp[j][k]
constexpr size_t OFF_ROWS   = OFF_WP     + 18432;                  // [N+1] int
constexpr size_t OFF_EIDX   = OFF_ROWS   + 200448;                 // [E] int
constexpr size_t OFF_GPART  = OFF_EIDX   + (size_t)E_*4;           // [G,128] f32

// K0: prep weights + zero bcnt. Blocks: 0 -> Wp att cols (+bcnt zero);
// 1..8 -> Wp main; 9..16 -> WT.
__global__ void k_prep(const float* __restrict__ Wg, const float* __restrict__ att_s,
                       const float* __restrict__ att_d, const float* __restrict__ W1,
                       __half* __restrict__ wp, __half* __restrict__ wt,
                       int* __restrict__ bcnt) {
    const int b = blockIdx.x, t = threadIdx.x;
    if (b == 0) {
        for (int i = t; i < NBUCK; i += 256) bcnt[i] = 0;
        // Wp[128+j'][k], j'=0..15: head h=j'&7, src half j'<8 else dst
        for (int idx = t; idx < 16 * 64; idx += 256) {
            int jp = idx >> 6, k = idx & 63;
            int h = jp & 7;
            const float* att = (jp < 8) ? att_s : att_d;
            float s = 0.f;
#pragma unroll
            for (int c = 0; c < 16; ++c)
                s = fmaf(Wg[k * 128 + h * 16 + c], att[h * 16 + c], s);
            wp[(128 + jp) * 64 + k] = __float2half(s);
        }
    } else if (b <= 8) {
        for (int idx = t; idx < 1024; idx += 256) {
            int e = (b - 1) * 1024 + idx;
            int j = e >> 6, k = e & 63;
            wp[j * 64 + k] = __float2half(Wg[k * 128 + j]);
        }
    } else {
        for (int idx = t; idx < 2048; idx += 256) {
            int e = (b - 9) * 2048 + idx;
            int j = e >> 7, k = e & 127;
            wt[j * 128 + k] = __float2half(W1[(size_t)k * 128 + j]);
        }
    }
}

// K1: merged bin (blocks 0..NBINB-1) + MFMA transform (blocks NBINB..).
__global__ __launch_bounds__(256) void k_binx(const int* __restrict__ src,
                                              const int* __restrict__ dst,
                                              int* __restrict__ bcnt,
                                              unsigned int* __restrict__ pairs,
                                              const float* __restrict__ feat,
                                              const __half* __restrict__ wp,
                                              __half* __restrict__ xh,
                                              float* __restrict__ asrc,
                                              float* __restrict__ adst) {
    union SMem {
        struct { int cnt[NBUCK]; int base[NBUCK]; } bin;
        struct { _Float16 fs[64][64]; _Float16 wp_s[144][64]; } xf;
    };
    __shared__ SMem sm;
    const int tid = threadIdx.x;

    if (blockIdx.x < NBINB) {
        // ---- binning branch ----
        int* cnt  = sm.bin.cnt;
        int* base = sm.bin.base;
        for (int i = tid; i < NBUCK; i += 256) cnt[i] = 0;
        __syncthreads();
        const int e0 = blockIdx.x * EPB;
        const int ne = min(EPB, E_ - e0);
        for (int i = tid; i < ne; i += 256) atomicAdd(&cnt[dst[e0 + i] >> 8], 1);
        __syncthreads();
        for (int i = tid; i < NBUCK; i += 256) {
            int c = cnt[i];
            base[i] = (c > 0) ? atomicAdd(&bcnt[i], c) : 0;
            cnt[i] = 0;
        }
        __syncthreads();
        for (int i = tid; i < ne; i += 256) {
            int d = dst[e0 + i];
            int s = src[e0 + i];
            int b = d >> 8;
            int p = base[b] + atomicAdd(&cnt[b], 1);
            pairs[(size_t)b * CAP + p] = ((unsigned int)(d & 255) << 16) | (unsigned int)s;
        }
        return;
    }

    // ---- transform branch ----
    const int base = (blockIdx.x - NBINB) * 64;
    for (int c = tid; c < 1152; c += 256) {
        int j = c >> 3, kk = (c & 7) * 8;
        *(float4*)&sm.xf.wp_s[j][kk] = *(const float4*)&wp[j * 64 + kk];
    }
    for (int c = tid; c < 512; c += 256) {
        int nl = c >> 3, kk = (c & 7) * 8;
        int n = base + nl;
        _Float16 h8[8];
        if (n < N_) {
            float4 f0 = *(const float4*)&feat[(size_t)n * 64 + kk];
            float4 f1 = *(const float4*)&feat[(size_t)n * 64 + kk + 4];
            h8[0]=(_Float16)f0.x; h8[1]=(_Float16)f0.y; h8[2]=(_Float16)f0.z; h8[3]=(_Float16)f0.w;
            h8[4]=(_Float16)f1.x; h8[5]=(_Float16)f1.y; h8[6]=(_Float16)f1.z; h8[7]=(_Float16)f1.w;
        } else {
#pragma unroll
            for (int q = 0; q < 8; ++q) h8[q] = (_Float16)0.f;
        }
        *(float4*)&sm.xf.fs[nl][kk] = *(float4*)h8;
    }
    __syncthreads();

    const int wv   = tid >> 6;
    const int lane = tid & 63;
    const int rc   = lane & 15;
    const int kh   = lane >> 4;

    f32x4 acc[9];
#pragma unroll
    for (int nt = 0; nt < 9; ++nt) acc[nt] = (f32x4){0.f, 0.f, 0.f, 0.f};

#pragma unroll
    for (int kt = 0; kt < 2; ++kt) {
        f16x8 a = *(const f16x8*)&sm.xf.fs[wv * 16 + rc][kt * 32 + kh * 8];
#pragma unroll
        for (int nt = 0; nt < 9; ++nt) {
            f16x8 bfr = *(const f16x8*)&sm.xf.wp_s[nt * 16 + rc][kt * 32 + kh * 8];
            acc[nt] = __builtin_amdgcn_mfma_f32_16x16x32_f16(a, bfr, acc[nt], 0, 0, 0);
        }
    }

#pragma unroll
    for (int r = 0; r < 4; ++r) {
        int n = base + wv * 16 + kh * 4 + r;
        if (n >= N_) continue;
#pragma unroll
        for (int nt = 0; nt < 8; ++nt)
            xh[(size_t)n * OUT_ + nt * 16 + rc] = __float2half(acc[nt][r]);
        if (rc < 8) asrc[n * H_ + rc] = acc[8][r];
        else        adst[n * H_ + (rc - 8)] = acc[8][r];
    }
}

// K2: per-bucket: inline bucket-prefix scan, local dst hist+scan -> rowstart,
// scatter eidx via LDS cursors.
__global__ __launch_bounds__(256) void k_scat3(const unsigned int* __restrict__ pairs,
                                               const int* __restrict__ bcnt,
                                               int* __restrict__ rowstart,
                                               int* __restrict__ eidx) {
    __shared__ int sh[256];
    __shared__ int cnt[256];
    __shared__ int cur[256];
    const int b = blockIdx.x;
    const int t = threadIdx.x;

    // inline exclusive prefix over bucket counts -> bstart_b
    int v0 = (t < NBUCK) ? bcnt[t] : 0;
    sh[t] = v0;
    __syncthreads();
    for (int off = 1; off < 256; off <<= 1) {
        int u = (t >= off) ? sh[t - off] : 0;
        __syncthreads();
        sh[t] += u;
        __syncthreads();
    }
    const int bstart_b = (b == 0) ? 0 : sh[b - 1];
    const int nb = bcnt[b];
    __syncthreads();

    cnt[t] = 0;
    __syncthreads();
    const size_t p0 = (size_t)b * CAP;
    for (int i = t; i < nb; i += 256)
        atomicAdd(&cnt[pairs[p0 + i] >> 16], 1);
    __syncthreads();
    int v = cnt[t];
    sh[t] = v;
    __syncthreads();
    for (int off = 1; off < 256; off <<= 1) {
        int u = (t >= off) ? sh[t - off] : 0;
        __syncthreads();
        sh[t] += u;
        __syncthreads();
    }
    int rs = bstart_b + sh[t] - v;   // exclusive
    int n = b * 256 + t;
    if (n < N_) rowstart[n] = rs;
    if (b == NBUCK - 1 && t == 0) rowstart[N_] = E_;
    cur[t] = rs;
    __syncthreads();
    for (int i = t; i < nb; i += 256) {
        unsigned int pk = pairs[p0 + i];
        int pos = atomicAdd(&cur[pk >> 16], 1);
        eidx[pos] = (int)(pk & 0xFFFFu);
    }
}

// K3: CSR aggregation (4-edge unroll; gathers independent of exp chain).
__global__ void k_agg(const int* __restrict__ rowstart, const int* __restrict__ eidx,
                      const __half* __restrict__ xh, const float* __restrict__ asrc,
                      const float* __restrict__ adst, const float* __restrict__ bias,
                      __half* __restrict__ embh) {
    const int dn   = blockIdx.x * 4 + (threadIdx.x >> 6);
    const int lane = threadIdx.x & 63;
    const int h    = lane >> 3;
    const float adst_h = adst[dn * H_ + h];
    const uint choff = (uint)lane * 2;

    const int beg = rowstart[dn];
    const int end = rowstart[dn + 1];

    float ax = 0.f, ay = 0.f, sw = 0.f;
    int i = beg;
    for (; i + 3 < end; i += 4) {
        int s0 = eidx[i];
        int s1 = eidx[i + 1];
        int s2 = eidx[i + 2];
        int s3 = eidx[i + 3];
        __half2 x0 = *(const __half2*)(xh + ((uint)s0 * OUT_ + choff));
        __half2 x1 = *(const __half2*)(xh + ((uint)s1 * OUT_ + choff));
        __half2 x2 = *(const __half2*)(xh + ((uint)s2 * OUT_ + choff));
        __half2 x3 = *(const __half2*)(xh + ((uint)s3 * OUT_ + choff));
        float a0 = asrc[(uint)s0 * H_ + h] + adst_h;
        float a1 = asrc[(uint)s1 * H_ + h] + adst_h;
        float a2 = asrc[(uint)s2 * H_ + h] + adst_h;
        float a3 = asrc[(uint)s3 * H_ + h] + adst_h;
        a0 = (a0 > 0.f) ? a0 : NEG_SLOPE * a0;
        a1 = (a1 > 0.f) ? a1 : NEG_SLOPE * a1;
        a2 = (a2 > 0.f) ? a2 : NEG_SLOPE * a2;
        a3 = (a3 > 0.f) ? a3 : NEG_SLOPE * a3;
        float w0 = __expf(a0);
        float w1 = __expf(a1);
        float w2 = __expf(a2);
        float w3 = __expf(a3);
        float2 f0 = __half22float2(x0);
        float2 f1 = __half22float2(x1);
        float2 f2 = __half22float2(x2);
        float2 f3 = __half22float2(x3);
        ax = fmaf(w0, f0.x, fmaf(w1, f1.x, fmaf(w2, f2.x, fmaf(w3, f3.x, ax))));
        ay = fmaf(w0, f0.y, fmaf(w1, f1.y, fmaf(w2, f2.y, fmaf(w3, f3.y, ay))));
        sw += (w0 + w1) + (w2 + w3);
    }
    for (; i < end; ++i) {
        int s0 = eidx[i];
        __half2 x0 = *(const __half2*)(xh + ((uint)s0 * OUT_ + choff));
        float a0 = asrc[(uint)s0 * H_ + h] + adst_h;
        a0 = (a0 > 0.f) ? a0 : NEG_SLOPE * a0;
        float w0 = __expf(a0);
        float2 f0 = __half22float2(x0);
        ax = fmaf(w0, f0.x, ax);
        ay = fmaf(w0, f0.y, ay);
        sw += w0;
    }
    {
        float al = asrc[(uint)dn * H_ + h] + adst_h;
        al = (al > 0.f) ? al : NEG_SLOPE * al;
        float w = __expf(al);
        __half2 xv = *(const __half2*)(xh + ((uint)dn * OUT_ + choff));
        float2 fv = __half22float2(xv);
        ax = fmaf(w, fv.x, ax);
        ay = fmaf(w, fv.y, ay);
        sw += w;
    }
    float ox = ax / sw + bias[lane * 2];
    float oy = ay / sw + bias[lane * 2 + 1];
    ox = (ox > 0.f) ? ox : expm1f(ox);
    oy = (oy > 0.f) ? oy : expm1f(oy);
    *(__half2*)&embh[(size_t)dn * OUT_ + lane * 2] = __floats2half2_rn(ox, oy);
}

// K4: fused mean-pool + graph head. Block g: binary-search node range (batch
// sorted), direct-sum embh rows, gemb -> output, gpart = gemb @ W1b + b1.
__global__ void k_pg(const __half* __restrict__ embh, const int* __restrict__ batch,
                     const float* __restrict__ W1, const float* __restrict__ b1,
                     float* __restrict__ outg, float* __restrict__ gpart) {
    const int g = blockIdx.x;
    const int j = threadIdx.x;   // 128
    int lo = 0, hi = N_;
    while (lo < hi) { int m = (lo + hi) >> 1; if (batch[m] < g) lo = m + 1; else hi = m; }
    const int start = lo;
    hi = N_;
    while (lo < hi) { int m = (lo + hi) >> 1; if (batch[m] <= g) lo = m + 1; else hi = m; }
    const int end = lo;

    float acc = 0.f;
    for (int n = start; n < end; ++n)
        acc += __half2float(embh[(size_t)n * OUT_ + j]);
    float v = acc / fmaxf((float)(end - start), 1.f);

    __shared__ float ge[128];
    ge[j] = v;
    outg[g * 128 + j] = v;
    __syncthreads();
    float s = b1[j];
    const float* w = W1 + (size_t)128 * 128 + j;
    for (int k = 0; k < 128; ++k) s = fmaf(ge[k], w[(size_t)k * 128], s);
    gpart[g * 128 + j] = s;
}

// K5: MFMA decoder. 64 nodes/block, 4 waves.
__global__ __launch_bounds__(256) void k_dec3(const __half* __restrict__ embh,
                                              const __half* __restrict__ wtg,
                                              const float* __restrict__ gpart,
                                              const int* __restrict__ batch,
                                              const float* __restrict__ W2,
                                              const float* __restrict__ b2,
                                              float* __restrict__ scores) {
    __shared__ _Float16 wt_s[128][128];
    __shared__ _Float16 emb_s[64][128];
    __shared__ float    w2_s[128];
    const int base = blockIdx.x * 64;
    const int tid  = threadIdx.x;

    for (int c = tid; c < 2048; c += 256) {
        int j = c >> 4, kk = (c & 15) * 8;
        *(float4*)&wt_s[j][kk] = *(const float4*)&wtg[j * 128 + kk];
    }
    for (int c = tid; c < 1024; c += 256) {
        int nl = c >> 4, kk = (c & 15) * 8;
        int n = base + nl;
        if (n < N_)
            *(float4*)&emb_s[nl][kk] = *(const float4*)&embh[(size_t)n * 128 + kk];
        else
            *(float4*)&emb_s[nl][kk] = make_float4(0.f, 0.f, 0.f, 0.f);
    }
    if (tid < 128) w2_s[tid] = W2[tid];
    __syncthreads();

    const int wv   = tid >> 6;
    const int lane = tid & 63;
    const int rc   = lane & 15;
    const int kh   = lane >> 4;

    f32x4 acc[8];
#pragma unroll
    for (int nt = 0; nt < 8; ++nt) acc[nt] = (f32x4){0.f, 0.f, 0.f, 0.f};

#pragma unroll
    for (int kt = 0; kt < 4; ++kt) {
        f16x8 a = *(const f16x8*)&emb_s[wv * 16 + rc][kt * 32 + kh * 8];
#pragma unroll
        for (int nt = 0; nt < 8; ++nt) {
            f16x8 bfr = *(const f16x8*)&wt_s[nt * 16 + rc][kt * 32 + kh * 8];
            acc[nt] = __builtin_amdgcn_mfma_f32_16x16x32_f16(a, bfr, acc[nt], 0, 0, 0);
        }
    }

    const float b2v = b2[0];
    float s[4] = {0.f, 0.f, 0.f, 0.f};
    int   gi[4];
#pragma unroll
    for (int r = 0; r < 4; ++r) {
        int n = base + wv * 16 + kh * 4 + r;
        gi[r] = (n < N_) ? batch[n] : 0;
    }
#pragma unroll
    for (int nt = 0; nt < 8; ++nt) {
        int j = nt * 16 + rc;
        float w2 = w2_s[j];
#pragma unroll
        for (int r = 0; r < 4; ++r) {
            float hv = acc[nt][r] + gpart[(size_t)gi[r] * 128 + j];
            hv = (hv > 0.f) ? hv : 0.f;
            s[r] = fmaf(hv, w2, s[r]);
        }
    }
#pragma unroll
    for (int r = 0; r < 4; ++r) {
#pragma unroll
        for (int m = 8; m >= 1; m >>= 1) s[r] += __shfl_xor(s[r], m, 16);
    }
    if (rc == 0) {
#pragma unroll
        for (int r = 0; r < 4; ++r) {
            int n = base + wv * 16 + kh * 4 + r;
            if (n < N_) scores[n] = s[r] + b2v;
        }
    }
}

extern "C" void kernel_launch(void* const* d_in, const int* in_sizes, int n_in,
                              void* d_out, int out_size, void* d_ws, size_t ws_size,
                              hipStream_t stream) {
    const float* feat   = (const float*)d_in[0];
    const int*   ei     = (const int*)d_in[1];
    const int*   batch  = (const int*)d_in[2];
    const float* Wg     = (const float*)d_in[3];
    const float* att_s  = (const float*)d_in[4];
    const float* att_d  = (const float*)d_in[5];
    const float* bias_g = (const float*)d_in[6];
    const float* W1     = (const float*)d_in[7];
    const float* b1     = (const float*)d_in[8];
    const float* W2     = (const float*)d_in[9];
    const float* b2     = (const float*)d_in[10];
    char*  wsb = (char*)d_ws;
    float* out = (float*)d_out;

    const int* src = ei;        // edge_index[0]
    const int* dst = ei + E_;   // edge_index[1]

    __half* XH    = (__half*)(wsb + OFF_X);
    __half* EMBH  = (__half*)(wsb + OFF_EMBH);
    float*  ASRC  = (float*)(wsb + OFF_ASRC);
    float*  ADST  = (float*)(wsb + OFF_ADST);
    unsigned int* PAIRS = (unsigned int*)(wsb + OFF_PAIRS);
    int*    BCNT  = (int*)  (wsb + OFF_BCNT);
    __half* WT    = (__half*)(wsb + OFF_WT);
    __half* WP    = (__half*)(wsb + OFF_WP);
    int*    ROWS  = (int*)  (wsb + OFF_ROWS);
    int*    EIDX  = (int*)  (wsb + OFF_EIDX);
    float*  GPART = (float*)(wsb + OFF_GPART);

    k_prep<<<17, 256, 0, stream>>>(Wg, att_s, att_d, W1, WP, WT, BCNT);
    k_binx<<<NBINB + NXF, 256, 0, stream>>>(src, dst, BCNT, PAIRS,
                                            feat, WP, XH, ASRC, ADST);
    k_scat3<<<NBUCK, 256, 0, stream>>>(PAIRS, BCNT, ROWS, EIDX);
    k_agg<<<N_ / 4, 256, 0, stream>>>(ROWS, EIDX, XH, ASRC, ADST, bias_g, EMBH);
    k_pg<<<G_, 128, 0, stream>>>(EMBH, batch, W1, b1, out + N_, GPART);
    k_dec3<<<(N_ + 63) / 64, 256, 0, stream>>>(EMBH, WT, GPART, batch, W2, b2, out);
}

// Round 12
// 127.856 us; speedup vs baseline: 1.3295x; 1.3295x over previous
//
#include <hip/hip_runtime.h>
#include <hip/hip_bf16.h>
#include <hip/hip_fp16.h>

constexpr int N_   = 50000;
constexpr int E_   = 800000;
constexpr int G_   = 256;
constexpr int IN_  = 64;
constexpr int H_   = 8;
constexpr int OUT_ = 128;   // H*C
constexpr float NEG_SLOPE = 0.2f;
constexpr int NBUCK = (N_ + 255) / 256;     // 196 dst-buckets (dst>>8)
constexpr int EPB   = 4096;                 // edges per bin block
constexpr int NBINB = (E_ + EPB - 1) / EPB; // 196 bin blocks
constexpr int CAP   = 6144;                 // bucket capacity
constexpr int NXF   = (N_ + 63) / 64;       // 782 xform blocks

typedef _Float16 f16x8 __attribute__((ext_vector_type(8)));
typedef float    f32x4 __attribute__((ext_vector_type(4)));

// ---- workspace layout (byte offsets, 256B-aligned) ----
constexpr size_t OFF_X      = 0;                                   // [N,128] f16 xh
constexpr size_t OFF_EMBH   = OFF_X      + (size_t)N_*OUT_*2;      // [N,128] f16 emb
constexpr size_t OFF_ASRC   = OFF_X      + (size_t)N_*OUT_*4;      // [N,8] f32
constexpr size_t OFF_ADST   = OFF_ASRC   + (size_t)N_*H_*4;        // [N,8] f32
constexpr size_t OFF_PAIRS  = OFF_ADST   + (size_t)N_*H_*4;        // [NBUCK*CAP] u32
constexpr size_t OFF_BCNT   = OFF_PAIRS  + (size_t)NBUCK*CAP*4;    // [NBUCK] int
constexpr size_t OFF_WT     = OFF_BCNT   + 1024;                   // [128,128] f16 W1a^T
constexpr size_t OFF_WP     = OFF_WT     + 128*128*2;              // [144,64] f16 Wp[j][k]
constexpr size_t OFF_ROWS   = OFF_WP     + 18432;                  // [N+1] int
constexpr size_t OFF_EIDX   = OFF_ROWS   + 200448;                 // [E] int
constexpr size_t OFF_GPART  = OFF_EIDX   + (size_t)E_*4;           // [G,128] f32
constexpr size_t OFF_GSUM   = OFF_GPART  + (size_t)G_*OUT_*4;      // [G,128] f32 (zeroed by prep)

// K0: prep weights + zero bcnt/gsum. Blocks: 0 -> Wp att cols (+bcnt zero);
// 1..8 -> Wp main; 9..16 -> WT (+gsum zero).
__global__ void k_prep(const float* __restrict__ Wg, const float* __restrict__ att_s,
                       const float* __restrict__ att_d, const float* __restrict__ W1,
                       __half* __restrict__ wp, __half* __restrict__ wt,
                       int* __restrict__ bcnt, float* __restrict__ gsum) {
    const int b = blockIdx.x, t = threadIdx.x;
    if (b == 0) {
        for (int i = t; i < NBUCK; i += 256) bcnt[i] = 0;
        // Wp[128+j'][k], j'=0..15: head h=j'&7, src half j'<8 else dst
        for (int idx = t; idx < 16 * 64; idx += 256) {
            int jp = idx >> 6, k = idx & 63;
            int h = jp & 7;
            const float* att = (jp < 8) ? att_s : att_d;
            float s = 0.f;
#pragma unroll
            for (int c = 0; c < 16; ++c)
                s = fmaf(Wg[k * 128 + h * 16 + c], att[h * 16 + c], s);
            wp[(128 + jp) * 64 + k] = __float2half(s);
        }
    } else if (b <= 8) {
        for (int idx = t; idx < 1024; idx += 256) {
            int e = (b - 1) * 1024 + idx;
            int j = e >> 6, k = e & 63;
            wp[j * 64 + k] = __float2half(Wg[k * 128 + j]);
        }
    } else {
        for (int idx = t; idx < 2048; idx += 256) {
            int e = (b - 9) * 2048 + idx;
            int j = e >> 7, k = e & 127;
            wt[j * 128 + k] = __float2half(W1[(size_t)k * 128 + j]);
        }
        for (int idx = t; idx < 4096; idx += 256)
            gsum[(size_t)(b - 9) * 4096 + idx] = 0.f;
    }
}

// K1: merged bin (blocks 0..NBINB-1) + MFMA transform (blocks NBINB..).
__global__ __launch_bounds__(256) void k_binx(const int* __restrict__ src,
                                              const int* __restrict__ dst,
                                              int* __restrict__ bcnt,
                                              unsigned int* __restrict__ pairs,
                                              const float* __restrict__ feat,
                                              const __half* __restrict__ wp,
                                              __half* __restrict__ xh,
                                              float* __restrict__ asrc,
                                              float* __restrict__ adst) {
    union SMem {
        struct { int cnt[NBUCK]; int base[NBUCK]; } bin;
        struct { _Float16 fs[64][64]; _Float16 wp_s[144][64]; } xf;
    };
    __shared__ SMem sm;
    const int tid = threadIdx.x;

    if (blockIdx.x < NBINB) {
        int* cnt  = sm.bin.cnt;
        int* base = sm.bin.base;
        for (int i = tid; i < NBUCK; i += 256) cnt[i] = 0;
        __syncthreads();
        const int e0 = blockIdx.x * EPB;
        const int ne = min(EPB, E_ - e0);
        for (int i = tid; i < ne; i += 256) atomicAdd(&cnt[dst[e0 + i] >> 8], 1);
        __syncthreads();
        for (int i = tid; i < NBUCK; i += 256) {
            int c = cnt[i];
            base[i] = (c > 0) ? atomicAdd(&bcnt[i], c) : 0;
            cnt[i] = 0;
        }
        __syncthreads();
        for (int i = tid; i < ne; i += 256) {
            int d = dst[e0 + i];
            int s = src[e0 + i];
            int b = d >> 8;
            int p = base[b] + atomicAdd(&cnt[b], 1);
            pairs[(size_t)b * CAP + p] = ((unsigned int)(d & 255) << 16) | (unsigned int)s;
        }
        return;
    }

    const int base = (blockIdx.x - NBINB) * 64;
    for (int c = tid; c < 1152; c += 256) {
        int j = c >> 3, kk = (c & 7) * 8;
        *(float4*)&sm.xf.wp_s[j][kk] = *(const float4*)&wp[j * 64 + kk];
    }
    for (int c = tid; c < 512; c += 256) {
        int nl = c >> 3, kk = (c & 7) * 8;
        int n = base + nl;
        _Float16 h8[8];
        if (n < N_) {
            float4 f0 = *(const float4*)&feat[(size_t)n * 64 + kk];
            float4 f1 = *(const float4*)&feat[(size_t)n * 64 + kk + 4];
            h8[0]=(_Float16)f0.x; h8[1]=(_Float16)f0.y; h8[2]=(_Float16)f0.z; h8[3]=(_Float16)f0.w;
            h8[4]=(_Float16)f1.x; h8[5]=(_Float16)f1.y; h8[6]=(_Float16)f1.z; h8[7]=(_Float16)f1.w;
        } else {
#pragma unroll
            for (int q = 0; q < 8; ++q) h8[q] = (_Float16)0.f;
        }
        *(float4*)&sm.xf.fs[nl][kk] = *(float4*)h8;
    }
    __syncthreads();

    const int wv   = tid >> 6;
    const int lane = tid & 63;
    const int rc   = lane & 15;
    const int kh   = lane >> 4;

    f32x4 acc[9];
#pragma unroll
    for (int nt = 0; nt < 9; ++nt) acc[nt] = (f32x4){0.f, 0.f, 0.f, 0.f};

#pragma unroll
    for (int kt = 0; kt < 2; ++kt) {
        f16x8 a = *(const f16x8*)&sm.xf.fs[wv * 16 + rc][kt * 32 + kh * 8];
#pragma unroll
        for (int nt = 0; nt < 9; ++nt) {
            f16x8 bfr = *(const f16x8*)&sm.xf.wp_s[nt * 16 + rc][kt * 32 + kh * 8];
            acc[nt] = __builtin_amdgcn_mfma_f32_16x16x32_f16(a, bfr, acc[nt], 0, 0, 0);
        }
    }

#pragma unroll
    for (int r = 0; r < 4; ++r) {
        int n = base + wv * 16 + kh * 4 + r;
        if (n >= N_) continue;
#pragma unroll
        for (int nt = 0; nt < 8; ++nt)
            xh[(size_t)n * OUT_ + nt * 16 + rc] = __float2half(acc[nt][r]);
        if (rc < 8) asrc[n * H_ + rc] = acc[8][r];
        else        adst[n * H_ + (rc - 8)] = acc[8][r];
    }
}

// K2: per-bucket: inline bucket-prefix scan, local dst hist+scan -> rowstart,
// scatter eidx via LDS cursors.
__global__ __launch_bounds__(256) void k_scat3(const unsigned int* __restrict__ pairs,
                                               const int* __restrict__ bcnt,
                                               int* __restrict__ rowstart,
                                               int* __restrict__ eidx) {
    __shared__ int sh[256];
    __shared__ int cnt[256];
    __shared__ int cur[256];
    const int b = blockIdx.x;
    const int t = threadIdx.x;

    int v0 = (t < NBUCK) ? bcnt[t] : 0;
    sh[t] = v0;
    __syncthreads();
    for (int off = 1; off < 256; off <<= 1) {
        int u = (t >= off) ? sh[t - off] : 0;
        __syncthreads();
        sh[t] += u;
        __syncthreads();
    }
    const int bstart_b = (b == 0) ? 0 : sh[b - 1];
    const int nb = bcnt[b];
    __syncthreads();

    cnt[t] = 0;
    __syncthreads();
    const size_t p0 = (size_t)b * CAP;
    for (int i = t; i < nb; i += 256)
        atomicAdd(&cnt[pairs[p0 + i] >> 16], 1);
    __syncthreads();
    int v = cnt[t];
    sh[t] = v;
    __syncthreads();
    for (int off = 1; off < 256; off <<= 1) {
        int u = (t >= off) ? sh[t - off] : 0;
        __syncthreads();
        sh[t] += u;
        __syncthreads();
    }
    int rs = bstart_b + sh[t] - v;   // exclusive
    int n = b * 256 + t;
    if (n < N_) rowstart[n] = rs;
    if (b == NBUCK - 1 && t == 0) rowstart[N_] = E_;
    cur[t] = rs;
    __syncthreads();
    for (int i = t; i < nb; i += 256) {
        unsigned int pk = pairs[p0 + i];
        int pos = atomicAdd(&cur[pk >> 16], 1);
        eidx[pos] = (int)(pk & 0xFFFFu);
    }
}

// K3: CSR aggregation (4-edge unroll; gathers independent of exp chain).
__global__ void k_agg(const int* __restrict__ rowstart, const int* __restrict__ eidx,
                      const __half* __restrict__ xh, const float* __restrict__ asrc,
                      const float* __restrict__ adst, const float* __restrict__ bias,
                      __half* __restrict__ embh) {
    const int dn   = blockIdx.x * 4 + (threadIdx.x >> 6);
    const int lane = threadIdx.x & 63;
    const int h    = lane >> 3;
    const float adst_h = adst[dn * H_ + h];
    const uint choff = (uint)lane * 2;

    const int beg = rowstart[dn];
    const int end = rowstart[dn + 1];

    float ax = 0.f, ay = 0.f, sw = 0.f;
    int i = beg;
    for (; i + 3 < end; i += 4) {
        int s0 = eidx[i];
        int s1 = eidx[i + 1];
        int s2 = eidx[i + 2];
        int s3 = eidx[i + 3];
        __half2 x0 = *(const __half2*)(xh + ((uint)s0 * OUT_ + choff));
        __half2 x1 = *(const __half2*)(xh + ((uint)s1 * OUT_ + choff));
        __half2 x2 = *(const __half2*)(xh + ((uint)s2 * OUT_ + choff));
        __half2 x3 = *(const __half2*)(xh + ((uint)s3 * OUT_ + choff));
        float a0 = asrc[(uint)s0 * H_ + h] + adst_h;
        float a1 = asrc[(uint)s1 * H_ + h] + adst_h;
        float a2 = asrc[(uint)s2 * H_ + h] + adst_h;
        float a3 = asrc[(uint)s3 * H_ + h] + adst_h;
        a0 = (a0 > 0.f) ? a0 : NEG_SLOPE * a0;
        a1 = (a1 > 0.f) ? a1 : NEG_SLOPE * a1;
        a2 = (a2 > 0.f) ? a2 : NEG_SLOPE * a2;
        a3 = (a3 > 0.f) ? a3 : NEG_SLOPE * a3;
        float w0 = __expf(a0);
        float w1 = __expf(a1);
        float w2 = __expf(a2);
        float w3 = __expf(a3);
        float2 f0 = __half22float2(x0);
        float2 f1 = __half22float2(x1);
        float2 f2 = __half22float2(x2);
        float2 f3 = __half22float2(x3);
        ax = fmaf(w0, f0.x, fmaf(w1, f1.x, fmaf(w2, f2.x, fmaf(w3, f3.x, ax))));
        ay = fmaf(w0, f0.y, fmaf(w1, f1.y, fmaf(w2, f2.y, fmaf(w3, f3.y, ay))));
        sw += (w0 + w1) + (w2 + w3);
    }
    for (; i < end; ++i) {
        int s0 = eidx[i];
        __half2 x0 = *(const __half2*)(xh + ((uint)s0 * OUT_ + choff));
        float a0 = asrc[(uint)s0 * H_ + h] + adst_h;
        a0 = (a0 > 0.f) ? a0 : NEG_SLOPE * a0;
        float w0 = __expf(a0);
        float2 f0 = __half22float2(x0);
        ax = fmaf(w0, f0.x, ax);
        ay = fmaf(w0, f0.y, ay);
        sw += w0;
    }
    {
        float al = asrc[(uint)dn * H_ + h] + adst_h;
        al = (al > 0.f) ? al : NEG_SLOPE * al;
        float w = __expf(al);
        __half2 xv = *(const __half2*)(xh + ((uint)dn * OUT_ + choff));
        float2 fv = __half22float2(xv);
        ax = fmaf(w, fv.x, ax);
        ay = fmaf(w, fv.y, ay);
        sw += w;
    }
    float ox = ax / sw + bias[lane * 2];
    float oy = ay / sw + bias[lane * 2 + 1];
    ox = (ox > 0.f) ? ox : expm1f(ox);
    oy = (oy > 0.f) ? oy : expm1f(oy);
    *(__half2*)&embh[(size_t)dn * OUT_ + lane * 2] = __floats2half2_rn(ox, oy);
}

// K4: mean-pool numerator from f16 emb. 64 nodes/block, 16-node runs.
__global__ void k_pool(const __half* __restrict__ embh, const int* __restrict__ batch,
                       float* __restrict__ gsum) {
    int c   = threadIdx.x & 63;
    int grp = threadIdx.x >> 6;
    int base = blockIdx.x * 64 + grp * 16;
    float rx = 0.f, ry = 0.f;
    int gcur = -1;
    for (int i = 0; i < 16; ++i) {
        int n = base + i;
        if (n >= N_) break;
        int g = batch[n];
        if (g != gcur) {
            if (gcur >= 0) {
                unsafeAtomicAdd(&gsum[gcur * OUT_ + 2 * c], rx);
                unsafeAtomicAdd(&gsum[gcur * OUT_ + 2 * c + 1], ry);
            }
            gcur = g; rx = ry = 0.f;
        }
        __half2 v = *(const __half2*)&embh[(size_t)n * OUT_ + 2 * c];
        float2 f = __half22float2(v);
        rx += f.x; ry += f.y;
    }
    if (gcur >= 0) {
        unsafeAtomicAdd(&gsum[gcur * OUT_ + 2 * c], rx);
        unsafeAtomicAdd(&gsum[gcur * OUT_ + 2 * c + 1], ry);
    }
}

// K5: fused per-graph: count, gemb -> output, gpart = gemb @ W1b + b1.
__global__ void k_graph(const int* __restrict__ batch, const float* __restrict__ gsum,
                        const float* __restrict__ W1, const float* __restrict__ b1,
                        float* __restrict__ outg, float* __restrict__ gpart) {
    const int g = blockIdx.x;
    const int j = threadIdx.x;
    __shared__ float ge[128];
    __shared__ int cnt_s;
    if (j == 0) {
        int lo = 0, hi = N_;
        while (lo < hi) { int m = (lo + hi) >> 1; if (batch[m] < g) lo = m + 1; else hi = m; }
        int start = lo;
        lo = 0; hi = N_;
        while (lo < hi) { int m = (lo + hi) >> 1; if (batch[m] <= g) lo = m + 1; else hi = m; }
        cnt_s = lo - start;
    }
    __syncthreads();
    float v = gsum[g * 128 + j] / fmaxf((float)cnt_s, 1.f);
    ge[j] = v;
    outg[g * 128 + j] = v;
    __syncthreads();
    float s = b1[j];
    const float* w = W1 + (size_t)128 * 128 + j;
    for (int k = 0; k < 128; ++k) s = fmaf(ge[k], w[(size_t)k * 128], s);
    gpart[g * 128 + j] = s;
}

// K6: MFMA decoder. 64 nodes/block, 4 waves.
__global__ __launch_bounds__(256) void k_dec3(const __half* __restrict__ embh,
                                              const __half* __restrict__ wtg,
                                              const float* __restrict__ gpart,
                                              const int* __restrict__ batch,
                                              const float* __restrict__ W2,
                                              const float* __restrict__ b2,
                                              float* __restrict__ scores) {
    __shared__ _Float16 wt_s[128][128];
    __shared__ _Float16 emb_s[64][128];
    __shared__ float    w2_s[128];
    const int base = blockIdx.x * 64;
    const int tid  = threadIdx.x;

    for (int c = tid; c < 2048; c += 256) {
        int j = c >> 4, kk = (c & 15) * 8;
        *(float4*)&wt_s[j][kk] = *(const float4*)&wtg[j * 128 + kk];
    }
    for (int c = tid; c < 1024; c += 256) {
        int nl = c >> 4, kk = (c & 15) * 8;
        int n = base + nl;
        if (n < N_)
            *(float4*)&emb_s[nl][kk] = *(const float4*)&embh[(size_t)n * 128 + kk];
        else
            *(float4*)&emb_s[nl][kk] = make_float4(0.f, 0.f, 0.f, 0.f);
    }
    if (tid < 128) w2_s[tid] = W2[tid];
    __syncthreads();

    const int wv   = tid >> 6;
    const int lane = tid & 63;
    const int rc   = lane & 15;
    const int kh   = lane >> 4;

    f32x4 acc[8];
#pragma unroll
    for (int nt = 0; nt < 8; ++nt) acc[nt] = (f32x4){0.f, 0.f, 0.f, 0.f};

#pragma unroll
    for (int kt = 0; kt < 4; ++kt) {
        f16x8 a = *(const f16x8*)&emb_s[wv * 16 + rc][kt * 32 + kh * 8];
#pragma unroll
        for (int nt = 0; nt < 8; ++nt) {
            f16x8 bfr = *(const f16x8*)&wt_s[nt * 16 + rc][kt * 32 + kh * 8];
            acc[nt] = __builtin_amdgcn_mfma_f32_16x16x32_f16(a, bfr, acc[nt], 0, 0, 0);
        }
    }

    const float b2v = b2[0];
    float s[4] = {0.f, 0.f, 0.f, 0.f};
    int   gi[4];
#pragma unroll
    for (int r = 0; r < 4; ++r) {
        int n = base + wv * 16 + kh * 4 + r;
        gi[r] = (n < N_) ? batch[n] : 0;
    }
#pragma unroll
    for (int nt = 0; nt < 8; ++nt) {
        int j = nt * 16 + rc;
        float w2 = w2_s[j];
#pragma unroll
        for (int r = 0; r < 4; ++r) {
            float hv = acc[nt][r] + gpart[(size_t)gi[r] * 128 + j];
            hv = (hv > 0.f) ? hv : 0.f;
            s[r] = fmaf(hv, w2, s[r]);
        }
    }
#pragma unroll
    for (int r = 0; r < 4; ++r) {
#pragma unroll
        for (int m = 8; m >= 1; m >>= 1) s[r] += __shfl_xor(s[r], m, 16);
    }
    if (rc == 0) {
#pragma unroll
        for (int r = 0; r < 4; ++r) {
            int n = base + wv * 16 + kh * 4 + r;
            if (n < N_) scores[n] = s[r] + b2v;
        }
    }
}

extern "C" void kernel_launch(void* const* d_in, const int* in_sizes, int n_in,
                              void* d_out, int out_size, void* d_ws, size_t ws_size,
                              hipStream_t stream) {
    const float* feat   = (const float*)d_in[0];
    const int*   ei     = (const int*)d_in[1];
    const int*   batch  = (const int*)d_in[2];
    const float* Wg     = (const float*)d_in[3];
    const float* att_s  = (const float*)d_in[4];
    const float* att_d  = (const float*)d_in[5];
    const float* bias_g = (const float*)d_in[6];
    const float* W1     = (const float*)d_in[7];
    const float* b1     = (const float*)d_in[8];
    const float* W2     = (const float*)d_in[9];
    const float* b2     = (const float*)d_in[10];
    char*  wsb = (char*)d_ws;
    float* out = (float*)d_out;

    const int* src = ei;        // edge_index[0]
    const int* dst = ei + E_;   // edge_index[1]

    __half* XH    = (__half*)(wsb + OFF_X);
    __half* EMBH  = (__half*)(wsb + OFF_EMBH);
    float*  ASRC  = (float*)(wsb + OFF_ASRC);
    float*  ADST  = (float*)(wsb + OFF_ADST);
    unsigned int* PAIRS = (unsigned int*)(wsb + OFF_PAIRS);
    int*    BCNT  = (int*)  (wsb + OFF_BCNT);
    __half* WT    = (__half*)(wsb + OFF_WT);
    __half* WP    = (__half*)(wsb + OFF_WP);
    int*    ROWS  = (int*)  (wsb + OFF_ROWS);
    int*    EIDX  = (int*)  (wsb + OFF_EIDX);
    float*  GPART = (float*)(wsb + OFF_GPART);
    float*  GSUM  = (float*)(wsb + OFF_GSUM);

    k_prep<<<17, 256, 0, stream>>>(Wg, att_s, att_d, W1, WP, WT, BCNT, GSUM);
    k_binx<<<NBINB + NXF, 256, 0, stream>>>(src, dst, BCNT, PAIRS,
                                            feat, WP, XH, ASRC, ADST);
    k_scat3<<<NBUCK, 256, 0, stream>>>(PAIRS, BCNT, ROWS, EIDX);
    k_agg<<<N_ / 4, 256, 0, stream>>>(ROWS, EIDX, XH, ASRC, ADST, bias_g, EMBH);
    k_pool<<<(N_ + 63) / 64, 256, 0, stream>>>(EMBH, batch, GSUM);
    k_graph<<<G_, 128, 0, stream>>>(batch, GSUM, W1, b1, out + N_, GPART);
    k_dec3<<<(N_ + 63) / 64, 256, 0, stream>>>(EMBH, WT, GPART, batch, W2, b2, out);
}

// Round 13
// 127.628 us; speedup vs baseline: 1.3318x; 1.0018x over previous
//
#include <hip/hip_runtime.h>
#include <hip/hip_bf16.h>
#include <hip/hip_fp16.h>

constexpr int N_   = 50000;
constexpr int E_   = 800000;
constexpr int G_   = 256;
constexpr int IN_  = 64;
constexpr int H_   = 8;
constexpr int OUT_ = 128;   // H*C
constexpr float NEG_SLOPE = 0.2f;
constexpr int NBUCK = (N_ + 255) / 256;     // 196 dst-buckets (dst>>8)
constexpr int EPB   = 2048;                 // edges per bin block (r13: halved)
constexpr int NBINB = (E_ + EPB - 1) / EPB; // 391 bin blocks
constexpr int CAP   = 6144;                 // bucket capacity
constexpr int NXF   = (N_ + 63) / 64;       // 782 xform blocks

typedef _Float16 f16x8 __attribute__((ext_vector_type(8)));
typedef float    f32x4 __attribute__((ext_vector_type(4)));

// ---- workspace layout (byte offsets, 256B-aligned) ----
constexpr size_t OFF_X      = 0;                                   // [N,128] f16 xh
constexpr size_t OFF_EMBH   = OFF_X      + (size_t)N_*OUT_*2;      // [N,128] f16 emb
constexpr size_t OFF_ASRC   = OFF_X      + (size_t)N_*OUT_*4;      // [N,8] f32
constexpr size_t OFF_ADST   = OFF_ASRC   + (size_t)N_*H_*4;        // [N,8] f32
constexpr size_t OFF_PAIRS  = OFF_ADST   + (size_t)N_*H_*4;        // [NBUCK*CAP] u32
constexpr size_t OFF_BCNT   = OFF_PAIRS  + (size_t)NBUCK*CAP*4;    // [NBUCK] int
constexpr size_t OFF_WT     = OFF_BCNT   + 1024;                   // [128,128] f16 W1a^T
constexpr size_t OFF_WP     = OFF_WT     + 128*128*2;              // [144,64] f16 Wp[j][k]
constexpr size_t OFF_ROWS   = OFF_WP     + 18432;                  // [N+1] int
constexpr size_t OFF_EIDX   = OFF_ROWS   + 200448;                 // [E] int
constexpr size_t OFF_GPART  = OFF_EIDX   + (size_t)E_*4;           // [G,128] f32
constexpr size_t OFF_GSUM   = OFF_GPART  + (size_t)G_*OUT_*4;      // [G,128] f32 (zeroed by prep)

// K0: prep weights + zero bcnt/gsum. Blocks: 0 -> Wp att cols (+bcnt zero);
// 1..8 -> Wp main; 9..16 -> WT (+gsum zero).
__global__ void k_prep(const float* __restrict__ Wg, const float* __restrict__ att_s,
                       const float* __restrict__ att_d, const float* __restrict__ W1,
                       __half* __restrict__ wp, __half* __restrict__ wt,
                       int* __restrict__ bcnt, float* __restrict__ gsum) {
    const int b = blockIdx.x, t = threadIdx.x;
    if (b == 0) {
        for (int i = t; i < NBUCK; i += 256) bcnt[i] = 0;
        // Wp[128+j'][k], j'=0..15: head h=j'&7, src half j'<8 else dst
        for (int idx = t; idx < 16 * 64; idx += 256) {
            int jp = idx >> 6, k = idx & 63;
            int h = jp & 7;
            const float* att = (jp < 8) ? att_s : att_d;
            float s = 0.f;
#pragma unroll
            for (int c = 0; c < 16; ++c)
                s = fmaf(Wg[k * 128 + h * 16 + c], att[h * 16 + c], s);
            wp[(128 + jp) * 64 + k] = __float2half(s);
        }
    } else if (b <= 8) {
        for (int idx = t; idx < 1024; idx += 256) {
            int e = (b - 1) * 1024 + idx;
            int j = e >> 6, k = e & 63;
            wp[j * 64 + k] = __float2half(Wg[k * 128 + j]);
        }
    } else {
        for (int idx = t; idx < 2048; idx += 256) {
            int e = (b - 9) * 2048 + idx;
            int j = e >> 7, k = e & 127;
            wt[j * 128 + k] = __float2half(W1[(size_t)k * 128 + j]);
        }
        for (int idx = t; idx < 4096; idx += 256)
            gsum[(size_t)(b - 9) * 4096 + idx] = 0.f;
    }
}

// K1: merged bin (blocks 0..NBINB-1) + MFMA transform (blocks NBINB..).
__global__ __launch_bounds__(256) void k_binx(const int* __restrict__ src,
                                              const int* __restrict__ dst,
                                              int* __restrict__ bcnt,
                                              unsigned int* __restrict__ pairs,
                                              const float* __restrict__ feat,
                                              const __half* __restrict__ wp,
                                              __half* __restrict__ xh,
                                              float* __restrict__ asrc,
                                              float* __restrict__ adst) {
    union SMem {
        struct { int cnt[NBUCK]; int base[NBUCK]; } bin;
        struct { _Float16 fs[64][64]; _Float16 wp_s[144][64]; } xf;
    };
    __shared__ SMem sm;
    const int tid = threadIdx.x;

    if (blockIdx.x < NBINB) {
        int* cnt  = sm.bin.cnt;
        int* base = sm.bin.base;
        for (int i = tid; i < NBUCK; i += 256) cnt[i] = 0;
        __syncthreads();
        const int e0 = blockIdx.x * EPB;
        const int ne = min(EPB, E_ - e0);
        for (int i = tid; i < ne; i += 256) atomicAdd(&cnt[dst[e0 + i] >> 8], 1);
        __syncthreads();
        for (int i = tid; i < NBUCK; i += 256) {
            int c = cnt[i];
            base[i] = (c > 0) ? atomicAdd(&bcnt[i], c) : 0;
            cnt[i] = 0;
        }
        __syncthreads();
        for (int i = tid; i < ne; i += 256) {
            int d = dst[e0 + i];
            int s = src[e0 + i];
            int b = d >> 8;
            int p = base[b] + atomicAdd(&cnt[b], 1);
            pairs[(size_t)b * CAP + p] = ((unsigned int)(d & 255) << 16) | (unsigned int)s;
        }
        return;
    }

    const int base = (blockIdx.x - NBINB) * 64;
    for (int c = tid; c < 1152; c += 256) {
        int j = c >> 3, kk = (c & 7) * 8;
        *(float4*)&sm.xf.wp_s[j][kk] = *(const float4*)&wp[j * 64 + kk];
    }
    for (int c = tid; c < 512; c += 256) {
        int nl = c >> 3, kk = (c & 7) * 8;
        int n = base + nl;
        _Float16 h8[8];
        if (n < N_) {
            float4 f0 = *(const float4*)&feat[(size_t)n * 64 + kk];
            float4 f1 = *(const float4*)&feat[(size_t)n * 64 + kk + 4];
            h8[0]=(_Float16)f0.x; h8[1]=(_Float16)f0.y; h8[2]=(_Float16)f0.z; h8[3]=(_Float16)f0.w;
            h8[4]=(_Float16)f1.x; h8[5]=(_Float16)f1.y; h8[6]=(_Float16)f1.z; h8[7]=(_Float16)f1.w;
        } else {
#pragma unroll
            for (int q = 0; q < 8; ++q) h8[q] = (_Float16)0.f;
        }
        *(float4*)&sm.xf.fs[nl][kk] = *(float4*)h8;
    }
    __syncthreads();

    const int wv   = tid >> 6;
    const int lane = tid & 63;
    const int rc   = lane & 15;
    const int kh   = lane >> 4;

    f32x4 acc[9];
#pragma unroll
    for (int nt = 0; nt < 9; ++nt) acc[nt] = (f32x4){0.f, 0.f, 0.f, 0.f};

#pragma unroll
    for (int kt = 0; kt < 2; ++kt) {
        f16x8 a = *(const f16x8*)&sm.xf.fs[wv * 16 + rc][kt * 32 + kh * 8];
#pragma unroll
        for (int nt = 0; nt < 9; ++nt) {
            f16x8 bfr = *(const f16x8*)&sm.xf.wp_s[nt * 16 + rc][kt * 32 + kh * 8];
            acc[nt] = __builtin_amdgcn_mfma_f32_16x16x32_f16(a, bfr, acc[nt], 0, 0, 0);
        }
    }

#pragma unroll
    for (int r = 0; r < 4; ++r) {
        int n = base + wv * 16 + kh * 4 + r;
        if (n >= N_) continue;
#pragma unroll
        for (int nt = 0; nt < 8; ++nt)
            xh[(size_t)n * OUT_ + nt * 16 + rc] = __float2half(acc[nt][r]);
        if (rc < 8) asrc[n * H_ + rc] = acc[8][r];
        else        adst[n * H_ + (rc - 8)] = acc[8][r];
    }
}

// K2: per-bucket-half scatter. Block (b,half): hist both ranges (h0,h1),
// scan h0+h1 -> rowstart (half 0 writes), cursors offset by h0 for half 1,
// scatter own range into disjoint eidx windows.
__global__ __launch_bounds__(256) void k_scat3(const unsigned int* __restrict__ pairs,
                                               const int* __restrict__ bcnt,
                                               int* __restrict__ rowstart,
                                               int* __restrict__ eidx) {
    __shared__ int sh[256];
    __shared__ int h0[256];
    __shared__ int h1[256];
    __shared__ int cur[256];
    const int b    = blockIdx.x >> 1;
    const int half = blockIdx.x & 1;
    const int t    = threadIdx.x;

    // inline exclusive prefix over bucket counts -> bstart_b
    int v0 = (t < NBUCK) ? bcnt[t] : 0;
    sh[t] = v0;
    __syncthreads();
    for (int off = 1; off < 256; off <<= 1) {
        int u = (t >= off) ? sh[t - off] : 0;
        __syncthreads();
        sh[t] += u;
        __syncthreads();
    }
    const int bstart_b = (b == 0) ? 0 : sh[b - 1];
    const int nb = bcnt[b];
    const int nh = nb >> 1;
    __syncthreads();

    h0[t] = 0;
    h1[t] = 0;
    __syncthreads();
    const size_t p0 = (size_t)b * CAP;
    for (int i = t; i < nh; i += 256) atomicAdd(&h0[pairs[p0 + i] >> 16], 1);
    for (int i = nh + t; i < nb; i += 256) atomicAdd(&h1[pairs[p0 + i] >> 16], 1);
    __syncthreads();
    int v = h0[t] + h1[t];
    sh[t] = v;
    __syncthreads();
    for (int off = 1; off < 256; off <<= 1) {
        int u = (t >= off) ? sh[t - off] : 0;
        __syncthreads();
        sh[t] += u;
        __syncthreads();
    }
    int rs = bstart_b + sh[t] - v;   // exclusive
    if (half == 0) {
        int n = b * 256 + t;
        if (n < N_) rowstart[n] = rs;
        if (b == NBUCK - 1 && t == 0) rowstart[N_] = E_;
    }
    cur[t] = rs + (half ? h0[t] : 0);
    __syncthreads();
    const int ibeg = half ? nh : 0;
    const int iend = half ? nb : nh;
    for (int i = ibeg + t; i < iend; i += 256) {
        unsigned int pk = pairs[p0 + i];
        int pos = atomicAdd(&cur[pk >> 16], 1);
        eidx[pos] = (int)(pk & 0xFFFFu);
    }
}

// K3: CSR aggregation (4-edge unroll; gathers independent of exp chain).
__global__ void k_agg(const int* __restrict__ rowstart, const int* __restrict__ eidx,
                      const __half* __restrict__ xh, const float* __restrict__ asrc,
                      const float* __restrict__ adst, const float* __restrict__ bias,
                      __half* __restrict__ embh) {
    const int dn   = blockIdx.x * 4 + (threadIdx.x >> 6);
    const int lane = threadIdx.x & 63;
    const int h    = lane >> 3;
    const float adst_h = adst[dn * H_ + h];
    const uint choff = (uint)lane * 2;

    const int beg = rowstart[dn];
    const int end = rowstart[dn + 1];

    float ax = 0.f, ay = 0.f, sw = 0.f;
    int i = beg;
    for (; i + 3 < end; i += 4) {
        int s0 = eidx[i];
        int s1 = eidx[i + 1];
        int s2 = eidx[i + 2];
        int s3 = eidx[i + 3];
        __half2 x0 = *(const __half2*)(xh + ((uint)s0 * OUT_ + choff));
        __half2 x1 = *(const __half2*)(xh + ((uint)s1 * OUT_ + choff));
        __half2 x2 = *(const __half2*)(xh + ((uint)s2 * OUT_ + choff));
        __half2 x3 = *(const __half2*)(xh + ((uint)s3 * OUT_ + choff));
        float a0 = asrc[(uint)s0 * H_ + h] + adst_h;
        float a1 = asrc[(uint)s1 * H_ + h] + adst_h;
        float a2 = asrc[(uint)s2 * H_ + h] + adst_h;
        float a3 = asrc[(uint)s3 * H_ + h] + adst_h;
        a0 = (a0 > 0.f) ? a0 : NEG_SLOPE * a0;
        a1 = (a1 > 0.f) ? a1 : NEG_SLOPE * a1;
        a2 = (a2 > 0.f) ? a2 : NEG_SLOPE * a2;
        a3 = (a3 > 0.f) ? a3 : NEG_SLOPE * a3;
        float w0 = __expf(a0);
        float w1 = __expf(a1);
        float w2 = __expf(a2);
        float w3 = __expf(a3);
        float2 f0 = __half22float2(x0);
        float2 f1 = __half22float2(x1);
        float2 f2 = __half22float2(x2);
        float2 f3 = __half22float2(x3);
        ax = fmaf(w0, f0.x, fmaf(w1, f1.x, fmaf(w2, f2.x, fmaf(w3, f3.x, ax))));
        ay = fmaf(w0, f0.y, fmaf(w1, f1.y, fmaf(w2, f2.y, fmaf(w3, f3.y, ay))));
        sw += (w0 + w1) + (w2 + w3);
    }
    for (; i < end; ++i) {
        int s0 = eidx[i];
        __half2 x0 = *(const __half2*)(xh + ((uint)s0 * OUT_ + choff));
        float a0 = asrc[(uint)s0 * H_ + h] + adst_h;
        a0 = (a0 > 0.f) ? a0 : NEG_SLOPE * a0;
        float w0 = __expf(a0);
        float2 f0 = __half22float2(x0);
        ax = fmaf(w0, f0.x, ax);
        ay = fmaf(w0, f0.y, ay);
        sw += w0;
    }
    {
        float al = asrc[(uint)dn * H_ + h] + adst_h;
        al = (al > 0.f) ? al : NEG_SLOPE * al;
        float w = __expf(al);
        __half2 xv = *(const __half2*)(xh + ((uint)dn * OUT_ + choff));
        float2 fv = __half22float2(xv);
        ax = fmaf(w, fv.x, ax);
        ay = fmaf(w, fv.y, ay);
        sw += w;
    }
    float ox = ax / sw + bias[lane * 2];
    float oy = ay / sw + bias[lane * 2 + 1];
    ox = (ox > 0.f) ? ox : expm1f(ox);
    oy = (oy > 0.f) ? oy : expm1f(oy);
    *(__half2*)&embh[(size_t)dn * OUT_ + lane * 2] = __floats2half2_rn(ox, oy);
}

// K4: mean-pool numerator from f16 emb. 64 nodes/block, 16-node runs.
__global__ void k_pool(const __half* __restrict__ embh, const int* __restrict__ batch,
                       float* __restrict__ gsum) {
    int c   = threadIdx.x & 63;
    int grp = threadIdx.x >> 6;
    int base = blockIdx.x * 64 + grp * 16;
    float rx = 0.f, ry = 0.f;
    int gcur = -1;
    for (int i = 0; i < 16; ++i) {
        int n = base + i;
        if (n >= N_) break;
        int g = batch[n];
        if (g != gcur) {
            if (gcur >= 0) {
                unsafeAtomicAdd(&gsum[gcur * OUT_ + 2 * c], rx);
                unsafeAtomicAdd(&gsum[gcur * OUT_ + 2 * c + 1], ry);
            }
            gcur = g; rx = ry = 0.f;
        }
        __half2 v = *(const __half2*)&embh[(size_t)n * OUT_ + 2 * c];
        float2 f = __half22float2(v);
        rx += f.x; ry += f.y;
    }
    if (gcur >= 0) {
        unsafeAtomicAdd(&gsum[gcur * OUT_ + 2 * c], rx);
        unsafeAtomicAdd(&gsum[gcur * OUT_ + 2 * c + 1], ry);
    }
}

// K5: fused per-graph: count, gemb -> output, gpart = gemb @ W1b + b1.
__global__ void k_graph(const int* __restrict__ batch, const float* __restrict__ gsum,
                        const float* __restrict__ W1, const float* __restrict__ b1,
                        float* __restrict__ outg, float* __restrict__ gpart) {
    const int g = blockIdx.x;
    const int j = threadIdx.x;
    __shared__ float ge[128];
    __shared__ int cnt_s;
    if (j == 0) {
        int lo = 0, hi = N_;
        while (lo < hi) { int m = (lo + hi) >> 1; if (batch[m] < g) lo = m + 1; else hi = m; }
        int start = lo;
        lo = 0; hi = N_;
        while (lo < hi) { int m = (lo + hi) >> 1; if (batch[m] <= g) lo = m + 1; else hi = m; }
        cnt_s = lo - start;
    }
    __syncthreads();
    float v = gsum[g * 128 + j] / fmaxf((float)cnt_s, 1.f);
    ge[j] = v;
    outg[g * 128 + j] = v;
    __syncthreads();
    float s = b1[j];
    const float* w = W1 + (size_t)128 * 128 + j;
    for (int k = 0; k < 128; ++k) s = fmaf(ge[k], w[(size_t)k * 128], s);
    gpart[g * 128 + j] = s;
}

// K6: MFMA decoder. 64 nodes/block, 4 waves.
__global__ __launch_bounds__(256) void k_dec3(const __half* __restrict__ embh,
                                              const __half* __restrict__ wtg,
                                              const float* __restrict__ gpart,
                                              const int* __restrict__ batch,
                                              const float* __restrict__ W2,
                                              const float* __restrict__ b2,
                                              float* __restrict__ scores) {
    __shared__ _Float16 wt_s[128][128];
    __shared__ _Float16 emb_s[64][128];
    __shared__ float    w2_s[128];
    const int base = blockIdx.x * 64;
    const int tid  = threadIdx.x;

    for (int c = tid; c < 2048; c += 256) {
        int j = c >> 4, kk = (c & 15) * 8;
        *(float4*)&wt_s[j][kk] = *(const float4*)&wtg[j * 128 + kk];
    }
    for (int c = tid; c < 1024; c += 256) {
        int nl = c >> 4, kk = (c & 15) * 8;
        int n = base + nl;
        if (n < N_)
            *(float4*)&emb_s[nl][kk] = *(const float4*)&embh[(size_t)n * 128 + kk];
        else
            *(float4*)&emb_s[nl][kk] = make_float4(0.f, 0.f, 0.f, 0.f);
    }
    if (tid < 128) w2_s[tid] = W2[tid];
    __syncthreads();

    const int wv   = tid >> 6;
    const int lane = tid & 63;
    const int rc   = lane & 15;
    const int kh   = lane >> 4;

    f32x4 acc[8];
#pragma unroll
    for (int nt = 0; nt < 8; ++nt) acc[nt] = (f32x4){0.f, 0.f, 0.f, 0.f};

#pragma unroll
    for (int kt = 0; kt < 4; ++kt) {
        f16x8 a = *(const f16x8*)&emb_s[wv * 16 + rc][kt * 32 + kh * 8];
#pragma unroll
        for (int nt = 0; nt < 8; ++nt) {
            f16x8 bfr = *(const f16x8*)&wt_s[nt * 16 + rc][kt * 32 + kh * 8];
            acc[nt] = __builtin_amdgcn_mfma_f32_16x16x32_f16(a, bfr, acc[nt], 0, 0, 0);
        }
    }

    const float b2v = b2[0];
    float s[4] = {0.f, 0.f, 0.f, 0.f};
    int   gi[4];
#pragma unroll
    for (int r = 0; r < 4; ++r) {
        int n = base + wv * 16 + kh * 4 + r;
        gi[r] = (n < N_) ? batch[n] : 0;
    }
#pragma unroll
    for (int nt = 0; nt < 8; ++nt) {
        int j = nt * 16 + rc;
        float w2 = w2_s[j];
#pragma unroll
        for (int r = 0; r < 4; ++r) {
            float hv = acc[nt][r] + gpart[(size_t)gi[r] * 128 + j];
            hv = (hv > 0.f) ? hv : 0.f;
            s[r] = fmaf(hv, w2, s[r]);
        }
    }
#pragma unroll
    for (int r = 0; r < 4; ++r) {
#pragma unroll
        for (int m = 8; m >= 1; m >>= 1) s[r] += __shfl_xor(s[r], m, 16);
    }
    if (rc == 0) {
#pragma unroll
        for (int r = 0; r < 4; ++r) {
            int n = base + wv * 16 + kh * 4 + r;
            if (n < N_) scores[n] = s[r] + b2v;
        }
    }
}

extern "C" void kernel_launch(void* const* d_in, const int* in_sizes, int n_in,
                              void* d_out, int out_size, void* d_ws, size_t ws_size,
                              hipStream_t stream) {
    const float* feat   = (const float*)d_in[0];
    const int*   ei     = (const int*)d_in[1];
    const int*   batch  = (const int*)d_in[2];
    const float* Wg     = (const float*)d_in[3];
    const float* att_s  = (const float*)d_in[4];
    const float* att_d  = (const float*)d_in[5];
    const float* bias_g = (const float*)d_in[6];
    const float* W1     = (const float*)d_in[7];
    const float* b1     = (const float*)d_in[8];
    const float* W2     = (const float*)d_in[9];
    const float* b2     = (const float*)d_in[10];
    char*  wsb = (char*)d_ws;
    float* out = (float*)d_out;

    const int* src = ei;        // edge_index[0]
    const int* dst = ei + E_;   // edge_index[1]

    __half* XH    = (__half*)(wsb + OFF_X);
    __half* EMBH  = (__half*)(wsb + OFF_EMBH);
    float*  ASRC  = (float*)(wsb + OFF_ASRC);
    float*  ADST  = (float*)(wsb + OFF_ADST);
    unsigned int* PAIRS = (unsigned int*)(wsb + OFF_PAIRS);
    int*    BCNT  = (int*)  (wsb + OFF_BCNT);
    __half* WT    = (__half*)(wsb + OFF_WT);
    __half* WP    = (__half*)(wsb + OFF_WP);
    int*    ROWS  = (int*)  (wsb + OFF_ROWS);
    int*    EIDX  = (int*)  (wsb + OFF_EIDX);
    float*  GPART = (float*)(wsb + OFF_GPART);
    float*  GSUM  = (float*)(wsb + OFF_GSUM);

    k_prep<<<17, 256, 0, stream>>>(Wg, att_s, att_d, W1, WP, WT, BCNT, GSUM);
    k_binx<<<NBINB + NXF, 256, 0, stream>>>(src, dst, BCNT, PAIRS,
                                            feat, WP, XH, ASRC, ADST);
    k_scat3<<<2 * NBUCK, 256, 0, stream>>>(PAIRS, BCNT, ROWS, EIDX);
    k_agg<<<N_ / 4, 256, 0, stream>>>(ROWS, EIDX, XH, ASRC, ADST, bias_g, EMBH);
    k_pool<<<(N_ + 63) / 64, 256, 0, stream>>>(EMBH, batch, GSUM);
    k_graph<<<G_, 128, 0, stream>>>(batch, GSUM, W1, b1, out + N_, GPART);
    k_dec3<<<(N_ + 63) / 64, 256, 0, stream>>>(EMBH, WT, GPART, batch, W2, b2, out);
}

// Round 14
// 120.303 us; speedup vs baseline: 1.4129x; 1.0609x over previous
//
#include <hip/hip_runtime.h>
#include <hip/hip_bf16.h>
#include <hip/hip_fp16.h>

constexpr int N_   = 50000;
constexpr int E_   = 800000;
constexpr int G_   = 256;
constexpr int IN_  = 64;
constexpr int H_   = 8;
constexpr int OUT_ = 128;   // H*C
constexpr float NEG_SLOPE = 0.2f;
constexpr int NBUCK = (N_ + 255) / 256;     // 196 dst-buckets (dst>>8)
constexpr int EPB   = 2048;                 // edges per bin block
constexpr int NBINB = (E_ + EPB - 1) / EPB; // 391 bin blocks
constexpr int CAP   = 6144;                 // bucket capacity
constexpr int NXF   = (N_ + 63) / 64;       // 782 xform blocks

typedef _Float16 f16x8 __attribute__((ext_vector_type(8)));
typedef float    f32x4 __attribute__((ext_vector_type(4)));

// ---- workspace layout (byte offsets, 256B-aligned) ----
constexpr size_t OFF_X      = 0;                                   // [N,128] f16 xh
constexpr size_t OFF_EMBH   = OFF_X      + (size_t)N_*OUT_*2;      // [N,128] f16 emb
constexpr size_t OFF_ASRC   = OFF_X      + (size_t)N_*OUT_*4;      // [N,8] f32
constexpr size_t OFF_ADST   = OFF_ASRC   + (size_t)N_*H_*4;        // [N,8] f32
constexpr size_t OFF_PAIRS  = OFF_ADST   + (size_t)N_*H_*4;        // [NBUCK*CAP] u32
constexpr size_t OFF_BCNT   = OFF_PAIRS  + (size_t)NBUCK*CAP*4;    // [NBUCK] int
constexpr size_t OFF_WT     = OFF_BCNT   + 1024;                   // [128,128] f16 W1a^T
constexpr size_t OFF_WP     = OFF_WT     + 128*128*2;              // [144,64] f16 Wp[j][k]
constexpr size_t OFF_ROWS   = OFF_WP     + 18432;                  // [N+1] int
constexpr size_t OFF_EIDX   = OFF_ROWS   + 200448;                 // [E] int
constexpr size_t OFF_GPART  = OFF_EIDX   + (size_t)E_*4;           // [G,128] f32
constexpr size_t OFF_GSUM   = OFF_GPART  + (size_t)G_*OUT_*4;      // [G,128] f32 (zeroed by prep)

// K0: prep weights + zero bcnt/gsum.
__global__ void k_prep(const float* __restrict__ Wg, const float* __restrict__ att_s,
                       const float* __restrict__ att_d, const float* __restrict__ W1,
                       __half* __restrict__ wp, __half* __restrict__ wt,
                       int* __restrict__ bcnt, float* __restrict__ gsum) {
    const int b = blockIdx.x, t = threadIdx.x;
    if (b == 0) {
        for (int i = t; i < NBUCK; i += 256) bcnt[i] = 0;
        for (int idx = t; idx < 16 * 64; idx += 256) {
            int jp = idx >> 6, k = idx & 63;
            int h = jp & 7;
            const float* att = (jp < 8) ? att_s : att_d;
            float s = 0.f;
#pragma unroll
            for (int c = 0; c < 16; ++c)
                s = fmaf(Wg[k * 128 + h * 16 + c], att[h * 16 + c], s);
            wp[(128 + jp) * 64 + k] = __float2half(s);
        }
    } else if (b <= 8) {
        for (int idx = t; idx < 1024; idx += 256) {
            int e = (b - 1) * 1024 + idx;
            int j = e >> 6, k = e & 63;
            wp[j * 64 + k] = __float2half(Wg[k * 128 + j]);
        }
    } else {
        for (int idx = t; idx < 2048; idx += 256) {
            int e = (b - 9) * 2048 + idx;
            int j = e >> 7, k = e & 127;
            wt[j * 128 + k] = __float2half(W1[(size_t)k * 128 + j]);
        }
        for (int idx = t; idx < 4096; idx += 256)
            gsum[(size_t)(b - 9) * 4096 + idx] = 0.f;
    }
}

// K1: merged bin (blocks 0..NBINB-1) + MFMA transform (blocks NBINB..).
__global__ __launch_bounds__(256) void k_binx(const int* __restrict__ src,
                                              const int* __restrict__ dst,
                                              int* __restrict__ bcnt,
                                              unsigned int* __restrict__ pairs,
                                              const float* __restrict__ feat,
                                              const __half* __restrict__ wp,
                                              __half* __restrict__ xh,
                                              float* __restrict__ asrc,
                                              float* __restrict__ adst) {
    union SMem {
        struct { int cnt[NBUCK]; int base[NBUCK]; } bin;
        struct { _Float16 fs[64][64]; _Float16 wp_s[144][64]; } xf;
    };
    __shared__ SMem sm;
    const int tid = threadIdx.x;

    if (blockIdx.x < NBINB) {
        int* cnt  = sm.bin.cnt;
        int* base = sm.bin.base;
        for (int i = tid; i < NBUCK; i += 256) cnt[i] = 0;
        __syncthreads();
        const int e0 = blockIdx.x * EPB;
        const int ne = min(EPB, E_ - e0);
        for (int i = tid; i < ne; i += 256) atomicAdd(&cnt[dst[e0 + i] >> 8], 1);
        __syncthreads();
        for (int i = tid; i < NBUCK; i += 256) {
            int c = cnt[i];
            base[i] = (c > 0) ? atomicAdd(&bcnt[i], c) : 0;
            cnt[i] = 0;
        }
        __syncthreads();
        for (int i = tid; i < ne; i += 256) {
            int d = dst[e0 + i];
            int s = src[e0 + i];
            int b = d >> 8;
            int p = base[b] + atomicAdd(&cnt[b], 1);
            pairs[(size_t)b * CAP + p] = ((unsigned int)(d & 255) << 16) | (unsigned int)s;
        }
        return;
    }

    const int base = (blockIdx.x - NBINB) * 64;
    for (int c = tid; c < 1152; c += 256) {
        int j = c >> 3, kk = (c & 7) * 8;
        *(float4*)&sm.xf.wp_s[j][kk] = *(const float4*)&wp[j * 64 + kk];
    }
    for (int c = tid; c < 512; c += 256) {
        int nl = c >> 3, kk = (c & 7) * 8;
        int n = base + nl;
        _Float16 h8[8];
        if (n < N_) {
            float4 f0 = *(const float4*)&feat[(size_t)n * 64 + kk];
            float4 f1 = *(const float4*)&feat[(size_t)n * 64 + kk + 4];
            h8[0]=(_Float16)f0.x; h8[1]=(_Float16)f0.y; h8[2]=(_Float16)f0.z; h8[3]=(_Float16)f0.w;
            h8[4]=(_Float16)f1.x; h8[5]=(_Float16)f1.y; h8[6]=(_Float16)f1.z; h8[7]=(_Float16)f1.w;
        } else {
#pragma unroll
            for (int q = 0; q < 8; ++q) h8[q] = (_Float16)0.f;
        }
        *(float4*)&sm.xf.fs[nl][kk] = *(float4*)h8;
    }
    __syncthreads();

    const int wv   = tid >> 6;
    const int lane = tid & 63;
    const int rc   = lane & 15;
    const int kh   = lane >> 4;

    f32x4 acc[9];
#pragma unroll
    for (int nt = 0; nt < 9; ++nt) acc[nt] = (f32x4){0.f, 0.f, 0.f, 0.f};

#pragma unroll
    for (int kt = 0; kt < 2; ++kt) {
        f16x8 a = *(const f16x8*)&sm.xf.fs[wv * 16 + rc][kt * 32 + kh * 8];
#pragma unroll
        for (int nt = 0; nt < 9; ++nt) {
            f16x8 bfr = *(const f16x8*)&sm.xf.wp_s[nt * 16 + rc][kt * 32 + kh * 8];
            acc[nt] = __builtin_amdgcn_mfma_f32_16x16x32_f16(a, bfr, acc[nt], 0, 0, 0);
        }
    }

#pragma unroll
    for (int r = 0; r < 4; ++r) {
        int n = base + wv * 16 + kh * 4 + r;
        if (n >= N_) continue;
#pragma unroll
        for (int nt = 0; nt < 8; ++nt)
            xh[(size_t)n * OUT_ + nt * 16 + rc] = __float2half(acc[nt][r]);
        if (rc < 8) asrc[n * H_ + rc] = acc[8][r];
        else        adst[n * H_ + (rc - 8)] = acc[8][r];
    }
}

// K2: per-bucket-half scatter (r13 structure).
__global__ __launch_bounds__(256) void k_scat3(const unsigned int* __restrict__ pairs,
                                               const int* __restrict__ bcnt,
                                               int* __restrict__ rowstart,
                                               int* __restrict__ eidx) {
    __shared__ int sh[256];
    __shared__ int h0[256];
    __shared__ int h1[256];
    __shared__ int cur[256];
    const int b    = blockIdx.x >> 1;
    const int half = blockIdx.x & 1;
    const int t    = threadIdx.x;

    int v0 = (t < NBUCK) ? bcnt[t] : 0;
    sh[t] = v0;
    __syncthreads();
    for (int off = 1; off < 256; off <<= 1) {
        int u = (t >= off) ? sh[t - off] : 0;
        __syncthreads();
        sh[t] += u;
        __syncthreads();
    }
    const int bstart_b = (b == 0) ? 0 : sh[b - 1];
    const int nb = bcnt[b];
    const int nh = nb >> 1;
    __syncthreads();

    h0[t] = 0;
    h1[t] = 0;
    __syncthreads();
    const size_t p0 = (size_t)b * CAP;
    for (int i = t; i < nh; i += 256) atomicAdd(&h0[pairs[p0 + i] >> 16], 1);
    for (int i = nh + t; i < nb; i += 256) atomicAdd(&h1[pairs[p0 + i] >> 16], 1);
    __syncthreads();
    int v = h0[t] + h1[t];
    sh[t] = v;
    __syncthreads();
    for (int off = 1; off < 256; off <<= 1) {
        int u = (t >= off) ? sh[t - off] : 0;
        __syncthreads();
        sh[t] += u;
        __syncthreads();
    }
    int rs = bstart_b + sh[t] - v;   // exclusive
    if (half == 0) {
        int n = b * 256 + t;
        if (n < N_) rowstart[n] = rs;
        if (b == NBUCK - 1 && t == 0) rowstart[N_] = E_;
    }
    cur[t] = rs + (half ? h0[t] : 0);
    __syncthreads();
    const int ibeg = half ? nh : 0;
    const int iend = half ? nb : nh;
    for (int i = ibeg + t; i < iend; i += 256) {
        unsigned int pk = pairs[p0 + i];
        int pos = atomicAdd(&cur[pk >> 16], 1);
        eidx[pos] = (int)(pk & 0xFFFFu);
    }
}

// K3: CSR aggregation (8-edge unroll) + fused mean-pool (cross-wave LDS merge
// + run-length atomics into gsum).
__global__ void k_agg(const int* __restrict__ rowstart, const int* __restrict__ eidx,
                      const __half* __restrict__ xh, const float* __restrict__ asrc,
                      const float* __restrict__ adst, const float* __restrict__ bias,
                      const int* __restrict__ batch, float* __restrict__ gsum,
                      __half* __restrict__ embh) {
    const int wvi  = threadIdx.x >> 6;
    const int dn   = blockIdx.x * 4 + wvi;
    const int lane = threadIdx.x & 63;
    const int h    = lane >> 3;
    const float adst_h = adst[dn * H_ + h];
    const uint choff = (uint)lane * 2;

    const int beg = rowstart[dn];
    const int end = rowstart[dn + 1];

    float ax = 0.f, ay = 0.f, sw = 0.f;
    int i = beg;
    for (; i + 7 < end; i += 8) {
        int s0 = eidx[i];
        int s1 = eidx[i + 1];
        int s2 = eidx[i + 2];
        int s3 = eidx[i + 3];
        int s4 = eidx[i + 4];
        int s5 = eidx[i + 5];
        int s6 = eidx[i + 6];
        int s7 = eidx[i + 7];
        __half2 x0 = *(const __half2*)(xh + ((uint)s0 * OUT_ + choff));
        __half2 x1 = *(const __half2*)(xh + ((uint)s1 * OUT_ + choff));
        __half2 x2 = *(const __half2*)(xh + ((uint)s2 * OUT_ + choff));
        __half2 x3 = *(const __half2*)(xh + ((uint)s3 * OUT_ + choff));
        __half2 x4 = *(const __half2*)(xh + ((uint)s4 * OUT_ + choff));
        __half2 x5 = *(const __half2*)(xh + ((uint)s5 * OUT_ + choff));
        __half2 x6 = *(const __half2*)(xh + ((uint)s6 * OUT_ + choff));
        __half2 x7 = *(const __half2*)(xh + ((uint)s7 * OUT_ + choff));
        float a0 = asrc[(uint)s0 * H_ + h] + adst_h;
        float a1 = asrc[(uint)s1 * H_ + h] + adst_h;
        float a2 = asrc[(uint)s2 * H_ + h] + adst_h;
        float a3 = asrc[(uint)s3 * H_ + h] + adst_h;
        float a4 = asrc[(uint)s4 * H_ + h] + adst_h;
        float a5 = asrc[(uint)s5 * H_ + h] + adst_h;
        float a6 = asrc[(uint)s6 * H_ + h] + adst_h;
        float a7 = asrc[(uint)s7 * H_ + h] + adst_h;
        a0 = (a0 > 0.f) ? a0 : NEG_SLOPE * a0;
        a1 = (a1 > 0.f) ? a1 : NEG_SLOPE * a1;
        a2 = (a2 > 0.f) ? a2 : NEG_SLOPE * a2;
        a3 = (a3 > 0.f) ? a3 : NEG_SLOPE * a3;
        a4 = (a4 > 0.f) ? a4 : NEG_SLOPE * a4;
        a5 = (a5 > 0.f) ? a5 : NEG_SLOPE * a5;
        a6 = (a6 > 0.f) ? a6 : NEG_SLOPE * a6;
        a7 = (a7 > 0.f) ? a7 : NEG_SLOPE * a7;
        float w0 = __expf(a0);
        float w1 = __expf(a1);
        float w2 = __expf(a2);
        float w3 = __expf(a3);
        float w4 = __expf(a4);
        float w5 = __expf(a5);
        float w6 = __expf(a6);
        float w7 = __expf(a7);
        float2 f0 = __half22float2(x0);
        float2 f1 = __half22float2(x1);
        float2 f2 = __half22float2(x2);
        float2 f3 = __half22float2(x3);
        float2 f4 = __half22float2(x4);
        float2 f5 = __half22float2(x5);
        float2 f6 = __half22float2(x6);
        float2 f7 = __half22float2(x7);
        ax = fmaf(w0, f0.x, fmaf(w1, f1.x, fmaf(w2, f2.x, fmaf(w3, f3.x, ax))));
        ax = fmaf(w4, f4.x, fmaf(w5, f5.x, fmaf(w6, f6.x, fmaf(w7, f7.x, ax))));
        ay = fmaf(w0, f0.y, fmaf(w1, f1.y, fmaf(w2, f2.y, fmaf(w3, f3.y, ay))));
        ay = fmaf(w4, f4.y, fmaf(w5, f5.y, fmaf(w6, f6.y, fmaf(w7, f7.y, ay))));
        sw += ((w0 + w1) + (w2 + w3)) + ((w4 + w5) + (w6 + w7));
    }
    for (; i + 3 < end; i += 4) {
        int s0 = eidx[i];
        int s1 = eidx[i + 1];
        int s2 = eidx[i + 2];
        int s3 = eidx[i + 3];
        __half2 x0 = *(const __half2*)(xh + ((uint)s0 * OUT_ + choff));
        __half2 x1 = *(const __half2*)(xh + ((uint)s1 * OUT_ + choff));
        __half2 x2 = *(const __half2*)(xh + ((uint)s2 * OUT_ + choff));
        __half2 x3 = *(const __half2*)(xh + ((uint)s3 * OUT_ + choff));
        float a0 = asrc[(uint)s0 * H_ + h] + adst_h;
        float a1 = asrc[(uint)s1 * H_ + h] + adst_h;
        float a2 = asrc[(uint)s2 * H_ + h] + adst_h;
        float a3 = asrc[(uint)s3 * H_ + h] + adst_h;
        a0 = (a0 > 0.f) ? a0 : NEG_SLOPE * a0;
        a1 = (a1 > 0.f) ? a1 : NEG_SLOPE * a1;
        a2 = (a2 > 0.f) ? a2 : NEG_SLOPE * a2;
        a3 = (a3 > 0.f) ? a3 : NEG_SLOPE * a3;
        float w0 = __expf(a0);
        float w1 = __expf(a1);
        float w2 = __expf(a2);
        float w3 = __expf(a3);
        float2 f0 = __half22float2(x0);
        float2 f1 = __half22float2(x1);
        float2 f2 = __half22float2(x2);
        float2 f3 = __half22float2(x3);
        ax = fmaf(w0, f0.x, fmaf(w1, f1.x, fmaf(w2, f2.x, fmaf(w3, f3.x, ax))));
        ay = fmaf(w0, f0.y, fmaf(w1, f1.y, fmaf(w2, f2.y, fmaf(w3, f3.y, ay))));
        sw += (w0 + w1) + (w2 + w3);
    }
    for (; i < end; ++i) {
        int s0 = eidx[i];
        __half2 x0 = *(const __half2*)(xh + ((uint)s0 * OUT_ + choff));
        float a0 = asrc[(uint)s0 * H_ + h] + adst_h;
        a0 = (a0 > 0.f) ? a0 : NEG_SLOPE * a0;
        float w0 = __expf(a0);
        float2 f0 = __half22float2(x0);
        ax = fmaf(w0, f0.x, ax);
        ay = fmaf(w0, f0.y, ay);
        sw += w0;
    }
    {
        float al = asrc[(uint)dn * H_ + h] + adst_h;
        al = (al > 0.f) ? al : NEG_SLOPE * al;
        float w = __expf(al);
        __half2 xv = *(const __half2*)(xh + ((uint)dn * OUT_ + choff));
        float2 fv = __half22float2(xv);
        ax = fmaf(w, fv.x, ax);
        ay = fmaf(w, fv.y, ay);
        sw += w;
    }
    float ox = ax / sw + bias[lane * 2];
    float oy = ay / sw + bias[lane * 2 + 1];
    ox = (ox > 0.f) ? ox : expm1f(ox);
    oy = (oy > 0.f) ? oy : expm1f(oy);
    *(__half2*)&embh[(size_t)dn * OUT_ + lane * 2] = __floats2half2_rn(ox, oy);

    // ---- fused mean-pool numerator: cross-wave merge + run-length atomics ----
    __shared__ float px[4][64];
    __shared__ float py[4][64];
    __shared__ int   gidv[4];
    px[wvi][lane] = ox;
    py[wvi][lane] = oy;
    if (lane == 0) gidv[wvi] = batch[dn];
    __syncthreads();
    if (wvi == 0) {
        float sx = px[0][lane], sy = py[0][lane];
        int gc = gidv[0];
#pragma unroll
        for (int w = 1; w < 4; ++w) {
            if (gidv[w] == gc) {
                sx += px[w][lane];
                sy += py[w][lane];
            } else {
                unsafeAtomicAdd(&gsum[gc * OUT_ + lane * 2], sx);
                unsafeAtomicAdd(&gsum[gc * OUT_ + lane * 2 + 1], sy);
                gc = gidv[w];
                sx = px[w][lane];
                sy = py[w][lane];
            }
        }
        unsafeAtomicAdd(&gsum[gc * OUT_ + lane * 2], sx);
        unsafeAtomicAdd(&gsum[gc * OUT_ + lane * 2 + 1], sy);
    }
}

// K4: fused per-graph: count, gemb -> output, gpart = gemb @ W1b + b1.
__global__ void k_graph(const int* __restrict__ batch, const float* __restrict__ gsum,
                        const float* __restrict__ W1, const float* __restrict__ b1,
                        float* __restrict__ outg, float* __restrict__ gpart) {
    const int g = blockIdx.x;
    const int j = threadIdx.x;
    __shared__ float ge[128];
    __shared__ int cnt_s;
    if (j == 0) {
        int lo = 0, hi = N_;
        while (lo < hi) { int m = (lo + hi) >> 1; if (batch[m] < g) lo = m + 1; else hi = m; }
        int start = lo;
        lo = 0; hi = N_;
        while (lo < hi) { int m = (lo + hi) >> 1; if (batch[m] <= g) lo = m + 1; else hi = m; }
        cnt_s = lo - start;
    }
    __syncthreads();
    float v = gsum[g * 128 + j] / fmaxf((float)cnt_s, 1.f);
    ge[j] = v;
    outg[g * 128 + j] = v;
    __syncthreads();
    float s = b1[j];
    const float* w = W1 + (size_t)128 * 128 + j;
    for (int k = 0; k < 128; ++k) s = fmaf(ge[k], w[(size_t)k * 128], s);
    gpart[g * 128 + j] = s;
}

// K5: MFMA decoder. 64 nodes/block, 4 waves.
__global__ __launch_bounds__(256) void k_dec3(const __half* __restrict__ embh,
                                              const __half* __restrict__ wtg,
                                              const float* __restrict__ gpart,
                                              const int* __restrict__ batch,
                                              const float* __restrict__ W2,
                                              const float* __restrict__ b2,
                                              float* __restrict__ scores) {
    __shared__ _Float16 wt_s[128][128];
    __shared__ _Float16 emb_s[64][128];
    __shared__ float    w2_s[128];
    const int base = blockIdx.x * 64;
    const int tid  = threadIdx.x;

    for (int c = tid; c < 2048; c += 256) {
        int j = c >> 4, kk = (c & 15) * 8;
        *(float4*)&wt_s[j][kk] = *(const float4*)&wtg[j * 128 + kk];
    }
    for (int c = tid; c < 1024; c += 256) {
        int nl = c >> 4, kk = (c & 15) * 8;
        int n = base + nl;
        if (n < N_)
            *(float4*)&emb_s[nl][kk] = *(const float4*)&embh[(size_t)n * 128 + kk];
        else
            *(float4*)&emb_s[nl][kk] = make_float4(0.f, 0.f, 0.f, 0.f);
    }
    if (tid < 128) w2_s[tid] = W2[tid];
    __syncthreads();

    const int wv   = tid >> 6;
    const int lane = tid & 63;
    const int rc   = lane & 15;
    const int kh   = lane >> 4;

    f32x4 acc[8];
#pragma unroll
    for (int nt = 0; nt < 8; ++nt) acc[nt] = (f32x4){0.f, 0.f, 0.f, 0.f};

#pragma unroll
    for (int kt = 0; kt < 4; ++kt) {
        f16x8 a = *(const f16x8*)&emb_s[wv * 16 + rc][kt * 32 + kh * 8];
#pragma unroll
        for (int nt = 0; nt < 8; ++nt) {
            f16x8 bfr = *(const f16x8*)&wt_s[nt * 16 + rc][kt * 32 + kh * 8];
            acc[nt] = __builtin_amdgcn_mfma_f32_16x16x32_f16(a, bfr, acc[nt], 0, 0, 0);
        }
    }

    const float b2v = b2[0];
    float s[4] = {0.f, 0.f, 0.f, 0.f};
    int   gi[4];
#pragma unroll
    for (int r = 0; r < 4; ++r) {
        int n = base + wv * 16 + kh * 4 + r;
        gi[r] = (n < N_) ? batch[n] : 0;
    }
#pragma unroll
    for (int nt = 0; nt < 8; ++nt) {
        int j = nt * 16 + rc;
        float w2 = w2_s[j];
#pragma unroll
        for (int r = 0; r < 4; ++r) {
            float hv = acc[nt][r] + gpart[(size_t)gi[r] * 128 + j];
            hv = (hv > 0.f) ? hv : 0.f;
            s[r] = fmaf(hv, w2, s[r]);
        }
    }
#pragma unroll
    for (int r = 0; r < 4; ++r) {
#pragma unroll
        for (int m = 8; m >= 1; m >>= 1) s[r] += __shfl_xor(s[r], m, 16);
    }
    if (rc == 0) {
#pragma unroll
        for (int r = 0; r < 4; ++r) {
            int n = base + wv * 16 + kh * 4 + r;
            if (n < N_) scores[n] = s[r] + b2v;
        }
    }
}

extern "C" void kernel_launch(void* const* d_in, const int* in_sizes, int n_in,
                              void* d_out, int out_size, void* d_ws, size_t ws_size,
                              hipStream_t stream) {
    const float* feat   = (const float*)d_in[0];
    const int*   ei     = (const int*)d_in[1];
    const int*   batch  = (const int*)d_in[2];
    const float* Wg     = (const float*)d_in[3];
    const float* att_s  = (const float*)d_in[4];
    const float* att_d  = (const float*)d_in[5];
    const float* bias_g = (const float*)d_in[6];
    const float* W1     = (const float*)d_in[7];
    const float* b1     = (const float*)d_in[8];
    const float* W2     = (const float*)d_in[9];
    const float* b2     = (const float*)d_in[10];
    char*  wsb = (char*)d_ws;
    float* out = (float*)d_out;

    const int* src = ei;        // edge_index[0]
    const int* dst = ei + E_;   // edge_index[1]

    __half* XH    = (__half*)(wsb + OFF_X);
    __half* EMBH  = (__half*)(wsb + OFF_EMBH);
    float*  ASRC  = (float*)(wsb + OFF_ASRC);
    float*  ADST  = (float*)(wsb + OFF_ADST);
    unsigned int* PAIRS = (unsigned int*)(wsb + OFF_PAIRS);
    int*    BCNT  = (int*)  (wsb + OFF_BCNT);
    __half* WT    = (__half*)(wsb + OFF_WT);
    __half* WP    = (__half*)(wsb + OFF_WP);
    int*    ROWS  = (int*)  (wsb + OFF_ROWS);
    int*    EIDX  = (int*)  (wsb + OFF_EIDX);
    float*  GPART = (float*)(wsb + OFF_GPART);
    float*  GSUM  = (float*)(wsb + OFF_GSUM);

    k_prep<<<17, 256, 0, stream>>>(Wg, att_s, att_d, W1, WP, WT, BCNT, GSUM);
    k_binx<<<NBINB + NXF, 256, 0, stream>>>(src, dst, BCNT, PAIRS,
                                            feat, WP, XH, ASRC, ADST);
    k_scat3<<<2 * NBUCK, 256, 0, stream>>>(PAIRS, BCNT, ROWS, EIDX);
    k_agg<<<N_ / 4, 256, 0, stream>>>(ROWS, EIDX, XH, ASRC, ADST, bias_g,
                                      batch, GSUM, EMBH);
    k_graph<<<G_, 128, 0, stream>>>(batch, GSUM, W1, b1, out + N_, GPART);
    k_dec3<<<(N_ + 63) / 64, 256, 0, stream>>>(EMBH, WT, GPART, batch, W2, b2, out);
}